// Round 17
// baseline (399.240 us; speedup 1.0000x reference)
//
#include <hip/hip_runtime.h>
#include <hip/hip_bf16.h>

#define B_TOT 2048
#define SEQ 64
#define CH 384
#define NH 12
#define HD 32
#define NC3 1152
#define LDP 392          // padded bf16 row stride for s_x / s_att (784 B)
#define QKS 40           // q/k tile row stride in u16 (80 B)
#define VS 72            // vt row stride in u16
#define HDSZ 7424        // per-(batch,head) u16: q 64*40 | k 64*40 | vt 32*72
#define NTSZ 6144        // packed weight: u16 per n-tile (12 kt * 512)
#define SFP 388          // f32 row stride for k_proj output staging (bank class 4/row)
#define QK_SCALE 0.17677669529663687f

typedef __attribute__((ext_vector_type(8))) short short8;   // 8 x bf16 MFMA frag
typedef __attribute__((ext_vector_type(4))) short short4v;
typedef __attribute__((ext_vector_type(4))) float f32x4;
typedef unsigned short u16;

__device__ __forceinline__ u16 f2bf(float f) {              // native cvt (measured: passes)
  __hip_bfloat16 h = __float2bfloat16(f);
  return *reinterpret_cast<u16*>(&h);
}
__device__ __forceinline__ float bf2f(u16 u) {
  return __uint_as_float(((unsigned int)u) << 16);
}

// 16B-granule XOR swizzle for the P LDS tile [64][64] bf16 (stride 64)
__device__ __forceinline__ int pswz(int row, int col) {
  return row * 64 + ((((col >> 3) ^ (row & 7)) << 3) | (col & 7));
}

// packed-weight dst index for element (k, n): fragment-major [nt][kt][q16][g4][e]
__device__ __forceinline__ int wpack(int k, int n) {
  int nt = n >> 4, q16 = n & 15;
  int kt = k >> 5, g4 = (k >> 3) & 3, e = k & 7;
  return ((nt * 12 + kt) * 64 + q16 * 4 + g4) * 8 + e;
}

// ---------------- K_AUX: one launch for prep + trunk + tvec ----------------------------------
__global__ __launch_bounds__(256) void k_aux(
    const float* __restrict__ qkv_w, const float* __restrict__ proj_w,
    const float* __restrict__ rpb_table, const int* __restrict__ rpb_index,
    const float* __restrict__ sigma, const float* __restrict__ w1,
    const float* __restrict__ b1, const float* __restrict__ w2,
    const float* __restrict__ b2, const float* __restrict__ gw,
    const float* __restrict__ gb, const float* __restrict__ bw,
    const float* __restrict__ bb, const float* __restrict__ temb,
    const float* __restrict__ qkvt_w, const float* __restrict__ qkv_b,
    u16* __restrict__ qkvwt, u16* __restrict__ projwt, u16* __restrict__ rpbz,
    float* __restrict__ inv1pg, float* __restrict__ nbias, float* __restrict__ tvec)
{
  __shared__ float shmem[16 * 384];
  const int bid = blockIdx.x;
  const int tid = threadIdx.x;

  if (bid < 2496) {                       // ---- prep (packed fragment-major weights) ----
    int idx = bid * 256 + tid;
    if (idx < CH * NC3) {
      int k = idx / NC3, n = idx - k * NC3;
      qkvwt[wpack(k, n)] = f2bf(qkv_w[idx]);
      return;
    }
    idx -= CH * NC3;
    if (idx < CH * CH) {
      int k = idx / CH, n = idx - k * CH;
      projwt[wpack(k, n)] = f2bf(proj_w[idx]);
      return;
    }
    idx -= CH * CH;
    if (idx < NH * SEQ * SEQ) {
      int h = idx >> 12, j = (idx >> 6) & 63, q = idx & 63;
      int jt = j >> 4, g4j = (j >> 2) & 3, r = j & 3;
      int qt = q >> 4, q16 = q & 15;
      int dst = (h * 16 + jt * 4 + qt) * 256 + g4j * 64 + q16 * 4 + r;
      rpbz[dst] = f2bf(rpb_table[rpb_index[q * 64 + j] * NH + h]);
    }
    return;
  }
  if (bid < 3008) {                       // ---- trunk (4 batches per block) ----
    float* sh = shmem;                    // [4][64]
    const int bt = tid >> 6, j = tid & 63;
    const int b = (bid - 2496) * 4 + bt;
    float ls = logf(fmaxf(sigma[b], 1e-6f));
    float z = fmaf(ls, w1[j], b1[j]);
    z = z / (1.f + __expf(-z));
    sh[bt * 64 + j] = z;
    __syncthreads();
    float a = b2[j];
    #pragma unroll 8
    for (int i = 0; i < 64; ++i) a = fmaf(sh[bt * 64 + i], w2[i * 64 + j], a);
    a = a / (1.f + __expf(-a));
    __syncthreads();
    sh[bt * 64 + j] = a;
    __syncthreads();
    if (j == 0) {
      float zg = gb[0];
      #pragma unroll 8
      for (int i = 0; i < 64; ++i) zg = fmaf(sh[bt * 64 + i], gw[i], zg);
      float gate = 1.f / (1.f + __expf(-zg));
      inv1pg[b] = 1.f / (1.f + gate);
    }
    if (j < NH) {
      float zb = bb[j];
      #pragma unroll 8
      for (int i = 0; i < 64; ++i) zb = fmaf(sh[bt * 64 + i], bw[i * NH + j], zb);
      nbias[b * NH + j] = zb;
    }
    return;
  }
  {                                       // ---- tvec ----
    const int bi = bid - 3008;
    const int brow = bi / 9, cseg = bi - brow * 9;
    const int cb = cseg * 128;
    for (int idx = tid; idx < 16 * 384; idx += 256) {
      int r = idx / 384, k = idx - r * 384;
      shmem[idx] = temb[(brow * 16 + r) * 384 + k];
    }
    __syncthreads();
    int cl = tid & 127, half = tid >> 7;
    float acc[8];
    #pragma unroll
    for (int i = 0; i < 8; ++i) acc[i] = 0.f;
    #pragma unroll 4
    for (int k = 0; k < 384; ++k) {
      float w = qkvt_w[k * NC3 + cb + cl];
      #pragma unroll
      for (int i = 0; i < 8; ++i) acc[i] = fmaf(shmem[(half * 8 + i) * 384 + k], w, acc[i]);
    }
    float qb = qkv_b[cb + cl];
    #pragma unroll
    for (int i = 0; i < 8; ++i)
      tvec[(brow * 16 + half * 8 + i) * NC3 + cb + cl] = acc[i] + qb;
  }
}

// ---------------- phase-A gemm: NT n-tiles x 8 m-tiles (2 batches), packed weights -----------
template<int NT>
__device__ __forceinline__ void gemm_qkv(f32x4 (&acc)[8][2],
                                         const u16* __restrict__ sx,
                                         const u16* __restrict__ qkvwt,
                                         int g, int nt0, int q16, int g4)
{
  const f32x4 fz = {0.f, 0.f, 0.f, 0.f};
  const u16* bp[NT];
  #pragma unroll
  for (int i = 0; i < NT; ++i) {
    int nt = nt0 + i;
    int hj = nt / 6, wi = nt - hj * 6;
    int mh = wi >> 1, hf = wi & 1;
    int ntg = mh * 24 + (g * 2 + hj) * 2 + hf;      // global n-tile index (of 72)
    bp[i] = qkvwt + ntg * NTSZ + q16 * 32 + g4 * 8; // wave reads contiguous 1 KB per (nt,kt)
  }
  #pragma unroll
  for (int m = 0; m < 8; ++m)
    #pragma unroll
    for (int i = 0; i < NT; ++i) acc[m][i] = fz;
  #pragma unroll 2
  for (int kt = 0; kt < 12; ++kt) {
    short8 af[8];
    #pragma unroll
    for (int m = 0; m < 8; ++m)
      af[m] = *reinterpret_cast<const short8*>(&sx[(m * 16 + q16) * LDP + kt * 32 + g4 * 8]);
    #pragma unroll
    for (int i = 0; i < NT; ++i) {
      short8 bf = *reinterpret_cast<const short8*>(bp[i] + kt * 512);
      #pragma unroll
      for (int m = 0; m < 8; ++m)
        acc[m][i] = __builtin_amdgcn_mfma_f32_16x16x32_bf16(af[m], bf, acc[m][i], 0, 0, 0);
    }
  }
}

// ---------------- phase-A epilogue: +tvec, scale, write q/k/vt to s_hd -----------------------
template<int NT>
__device__ __forceinline__ void epi_qkv(const f32x4 (&acc)[8][2], u16* __restrict__ shd,
                                        const float* __restrict__ tvb,
                                        int g, int nt0, int q16, int g4)
{
  #pragma unroll
  for (int i = 0; i < NT; ++i) {
    int nt = nt0 + i;
    int hj = nt / 6, wi = nt - hj * 6;
    int mh = wi >> 1, hf = wi & 1;
    int c = mh * CH + (g * 2 + hj) * HD + hf * 16 + q16;
    float tv0 = tvb[c], tv1 = tvb[NC3 + c];
    int cof = hf * 16 + q16;
    #pragma unroll
    for (int m = 0; m < 8; ++m) {
      int bt = m >> 2;
      u16* hbase = &shd[(bt * 2 + hj) * HDSZ];
      int mrow = (m & 3) * 16 + g4 * 4;
      f32x4 a = acc[m][i];
      float tvv = bt ? tv1 : tv0;
      if (mh == 0) {
        #pragma unroll
        for (int r = 0; r < 4; ++r)
          hbase[(mrow + r) * QKS + cof] = f2bf((a[r] + tvv) * QK_SCALE);
      } else if (mh == 1) {
        #pragma unroll
        for (int r = 0; r < 4; ++r)
          hbase[2560 + (mrow + r) * QKS + cof] = f2bf(a[r] + tvv);
      } else {
        short4v pk;
        #pragma unroll
        for (int r = 0; r < 4; ++r) pk[r] = (short)f2bf(a[r] + tvv);
        *reinterpret_cast<short4v*>(&hbase[5120 + cof * VS + mrow]) = pk;
      }
    }
  }
}

// ---------------- K3: per-(2-batch) QKV -> attention -> att (bf16, to ws) --------------------
// 512 thr = 8 waves = 2 waves/SIMD; LDS 159744 B -> 1 block/CU. (R16 structure: measured best.)
__global__ __launch_bounds__(512, 2) void k_attn(
    const float* __restrict__ x, const float* __restrict__ tvec,
    const float* __restrict__ inv1pg, const float* __restrict__ nbias,
    const u16* __restrict__ qkvwt, const u16* __restrict__ rpbz,
    u16* __restrict__ attw)
{
  __shared__ __align__(16) u16 s_x[128 * LDP];    // x[2 batches] bf16 (100352 B)
  __shared__ __align__(16) u16 s_hd[4 * HDSZ];    // [batch][head]: q|k|vt (59392 B)
  const f32x4 fz = {0.f, 0.f, 0.f, 0.f};

  const int b0 = blockIdx.x * 2;
  const int tid = threadIdx.x;
  const int w = tid >> 6, l = tid & 63;
  const int q16 = l & 15, g4 = l >> 4;

  // ---- stage x for 2 batches (fp32 -> bf16), coalesced float4 ----
  {
    const float* xb = x + (size_t)b0 * (SEQ * CH);
    #pragma unroll 4
    for (int it = 0; it < 24; ++it) {
      int fi = it * 512 + tid;            // float4 index; 96 per row, 128 rows
      int row = fi / 96, c4 = fi - row * 96;
      const float4 a = *reinterpret_cast<const float4*>(xb + fi * 4);
      short4v v;
      v[0] = (short)f2bf(a.x); v[1] = (short)f2bf(a.y);
      v[2] = (short)f2bf(a.z); v[3] = (short)f2bf(a.w);
      *reinterpret_cast<short4v*>(&s_x[row * LDP + c4 * 4]) = v;
    }
  }
  __syncthreads();

  const float invb0 = inv1pg[b0], invb1 = inv1pg[b0 + 1];
  const float* tvb = tvec + (size_t)b0 * NC3;

  const int nt0 = (w < 4) ? 2 * w : 8 + (w - 4);

  f32x4 acc[8][2];
  // prologue: gemm for group 0
  if (w < 4) gemm_qkv<2>(acc, s_x, qkvwt, 0, nt0, q16, g4);
  else       gemm_qkv<1>(acc, s_x, qkvwt, 0, nt0, q16, g4);

  for (int g = 0; g < 6; ++g) {
    if (g) __syncthreads();               // bar_a: pass2(g-1) done reading s_hd
    // ===== epilogue(g): acc -> s_hd =====
    if (w < 4) epi_qkv<2>(acc, s_hd, tvb, g, nt0, q16, g4);
    else       epi_qkv<1>(acc, s_hd, tvb, g, nt0, q16, g4);
    __syncthreads();                      // bar_b: q/k/vt ready

    // ===== pass1: QK^T + gate + softmax for tasks t=0,1 =====
    f32x4 st2[2][4];
    #pragma unroll
    for (int t = 0; t < 2; ++t) {
      const int tau = w * 2 + t;
      const int cmb = tau >> 2, qt = tau & 3;
      const int bt = cmb >> 1, hh = cmb & 1;
      const int h = g * 2 + hh;
      const u16* sq = &s_hd[cmb * HDSZ];
      const u16* sk = sq + 2560;
      const float inv = bt ? invb1 : invb0;
      const float nb = nbias[(b0 + bt) * NH + h];

      short4v rp4[4];
      #pragma unroll
      for (int jt = 0; jt < 4; ++jt)
        rp4[jt] = *reinterpret_cast<const short4v*>(
            &rpbz[(h * 16 + jt * 4 + qt) * 256 + g4 * 64 + q16 * 4]);

      short8 bq = *reinterpret_cast<const short8*>(&sq[(qt * 16 + q16) * QKS + g4 * 8]);
      #pragma unroll
      for (int jt = 0; jt < 4; ++jt) {
        short8 ak = *reinterpret_cast<const short8*>(&sk[(jt * 16 + q16) * QKS + g4 * 8]);
        st2[t][jt] = __builtin_amdgcn_mfma_f32_16x16x32_bf16(ak, bq, fz, 0, 0, 0);
      }
      float mx = -1e30f;
      #pragma unroll
      for (int jt = 0; jt < 4; ++jt)
        #pragma unroll
        for (int r = 0; r < 4; ++r) {
          float s = fmaf(st2[t][jt][r], inv, fmaf(bf2f((u16)rp4[jt][r]), inv, nb));
          st2[t][jt][r] = s;
          mx = fmaxf(mx, s);
        }
      mx = fmaxf(mx, __shfl_xor(mx, 16));
      mx = fmaxf(mx, __shfl_xor(mx, 32));
      float sum = 0.f;
      #pragma unroll
      for (int jt = 0; jt < 4; ++jt)
        #pragma unroll
        for (int r = 0; r < 4; ++r) {
          float p = __expf(st2[t][jt][r] - mx);
          st2[t][jt][r] = p;
          sum += p;
        }
      sum += __shfl_xor(sum, 16);
      sum += __shfl_xor(sum, 32);
      float rn = 1.f / sum;
      #pragma unroll
      for (int jt = 0; jt < 4; ++jt)
        #pragma unroll
        for (int r = 0; r < 4; ++r) st2[t][jt][r] *= rn;
    }
    __syncthreads();                      // bar_c: all q/k reads done before P overlay

    // ===== region R3: gemm(g+1) interleaved with pass2(g) by the scheduler =====
    if (g < 5) {
      if (w < 4) gemm_qkv<2>(acc, s_x, qkvwt, g + 1, nt0, q16, g4);
      else       gemm_qkv<1>(acc, s_x, qkvwt, g + 1, nt0, q16, g4);
    }
    #pragma unroll
    for (int t = 0; t < 2; ++t) {
      const int tau = w * 2 + t;
      const int cmb = tau >> 2, qt = tau & 3;
      const int bt = cmb >> 1, hh = cmb & 1;
      const int h = g * 2 + hh;
      u16* sq = &s_hd[cmb * HDSZ];
      const u16* svt = sq + 5120;
      u16* P = sq;                        // 64x64 bf16 swizzled, overlays q+k

      #pragma unroll
      for (int jt = 0; jt < 4; ++jt) {
        short4v pk;
        #pragma unroll
        for (int r = 0; r < 4; ++r) pk[r] = (short)f2bf(st2[t][jt][r]);
        *reinterpret_cast<short4v*>(&P[pswz(qt * 16 + q16, jt * 16 + 4 * g4)]) = pk;
      }
      f32x4 o[2];
      o[0] = fz; o[1] = fz;
      #pragma unroll
      for (int kk = 0; kk < 2; ++kk) {
        short8 ap = *reinterpret_cast<const short8*>(
            &P[pswz(qt * 16 + q16, kk * 32 + g4 * 8)]);
        #pragma unroll
        for (int dt = 0; dt < 2; ++dt) {
          short8 bv = *reinterpret_cast<const short8*>(
              &svt[(dt * 16 + q16) * VS + kk * 32 + g4 * 8]);
          o[dt] = __builtin_amdgcn_mfma_f32_16x16x32_bf16(ap, bv, o[dt], 0, 0, 0);
        }
      }
      u16* ab = attw + (size_t)(b0 + bt) * (SEQ * CH);
      #pragma unroll
      for (int dt = 0; dt < 2; ++dt)
        #pragma unroll
        for (int r = 0; r < 4; ++r)
          ab[(qt * 16 + g4 * 4 + r) * CH + h * HD + dt * 16 + q16] = f2bf(o[dt][r]);
    }
  }
}

// ---------------- K4: proj GEMM out = att @ projwt^T + b; 64-row tiles, packed weights -------
// Output now routed through LDS (reusing the att staging region) so global stores are
// fully coalesced float4 (consecutive lanes -> consecutive addresses).
__global__ __launch_bounds__(512, 3) void k_proj(
    const u16* __restrict__ attw, const u16* __restrict__ projwt,
    const float* __restrict__ proj_b, float* __restrict__ out)
{
  __shared__ __align__(16) u16 s_a[64 * LDP];     // att tile bf16 (50176 B); reused as f32 stage
  float* s_f = reinterpret_cast<float*>(s_a);     // [32][SFP=388] f32 (49664 B)
  const f32x4 fz = {0.f, 0.f, 0.f, 0.f};
  const int tid = threadIdx.x;
  const int w = tid >> 6, l = tid & 63;
  const int q16 = l & 15, g4 = l >> 4;
  const size_t row0 = (size_t)blockIdx.x * 64;

  {
    const u16* ab = attw + row0 * CH;
    #pragma unroll
    for (int it = 0; it < 6; ++it) {
      int slot = it * 512 + tid;
      int row = slot / 48, c8 = slot - row * 48;   // 48 short8 per 384-col row
      short8 v = *reinterpret_cast<const short8*>(ab + row * CH + c8 * 8);
      *reinterpret_cast<short8*>(&s_a[row * LDP + c8 * 8]) = v;
    }
  }
  __syncthreads();

  const u16* bpw[3]; float4 pb4[3];
  #pragma unroll
  for (int i = 0; i < 3; ++i) {
    int nt = w * 3 + i;
    bpw[i] = projwt + nt * NTSZ + q16 * 32 + g4 * 8;   // contiguous 1 KB per (nt,kt)
    pb4[i] = *reinterpret_cast<const float4*>(&proj_b[nt * 16 + 4 * g4]);
  }
  f32x4 acc[4][3];
  #pragma unroll
  for (int m = 0; m < 4; ++m)
    #pragma unroll
    for (int i = 0; i < 3; ++i) acc[m][i] = fz;
  #pragma unroll 2
  for (int kt = 0; kt < 12; ++kt) {
    short8 af[4];
    #pragma unroll
    for (int m = 0; m < 4; ++m)
      af[m] = *reinterpret_cast<const short8*>(&s_a[(m * 16 + q16) * LDP + kt * 32 + g4 * 8]);
    short8 bf[3];
    #pragma unroll
    for (int i = 0; i < 3; ++i)
      bf[i] = *reinterpret_cast<const short8*>(bpw[i] + kt * 512);
    #pragma unroll
    for (int i = 0; i < 3; ++i)
      #pragma unroll
      for (int m = 0; m < 4; ++m)
        acc[m][i] = __builtin_amdgcn_mfma_f32_16x16x32_bf16(bf[i], af[m], acc[m][i], 0, 0, 0);
  }

  // ---- output: two 32-row halves, LDS-transpose then fully-coalesced float4 stores ----
  #pragma unroll
  for (int h = 0; h < 2; ++h) {
    __syncthreads();   // h=0: all af reads done (s_a dead); h=1: half-0 reads done
    #pragma unroll
    for (int mm = 0; mm < 2; ++mm) {
      int m = h * 2 + mm;                 // m-tile (16 tokens)
      int tok = mm * 16 + q16;            // token within half [0,32)
      #pragma unroll
      for (int i = 0; i < 3; ++i) {
        int f0 = (w * 3 + i) * 16 + 4 * g4;
        float4 v;
        v.x = acc[m][i][0] + pb4[i].x;
        v.y = acc[m][i][1] + pb4[i].y;
        v.z = acc[m][i][2] + pb4[i].z;
        v.w = acc[m][i][3] + pb4[i].w;
        *reinterpret_cast<float4*>(&s_f[tok * SFP + f0]) = v;
      }
    }
    __syncthreads();
    float* ob = out + (row0 + h * 32) * CH;
    #pragma unroll
    for (int it = 0; it < 6; ++it) {
      int slot = it * 512 + tid;
      int row = slot / 96, c4 = slot - row * 96;   // 96 float4 per 384-col row
      float4 v = *reinterpret_cast<const float4*>(&s_f[row * SFP + c4 * 4]);
      *reinterpret_cast<float4*>(&ob[row * CH + c4 * 4]) = v;
    }
  }
}

// ---------------- launcher ----------------
extern "C" void kernel_launch(void* const* d_in, const int* in_sizes, int n_in,
                              void* d_out, int out_size, void* d_ws, size_t ws_size,
                              hipStream_t stream) {
  const float* x       = (const float*)d_in[0];
  const float* temb    = (const float*)d_in[1];
  const float* sigma   = (const float*)d_in[2];
  const float* qkv_w   = (const float*)d_in[3];
  const float* qkv_b   = (const float*)d_in[4];
  const float* qkvt_w  = (const float*)d_in[5];
  const float* w1      = (const float*)d_in[6];
  const float* b1      = (const float*)d_in[7];
  const float* w2      = (const float*)d_in[8];
  const float* b2      = (const float*)d_in[9];
  const float* gw      = (const float*)d_in[10];
  const float* gb      = (const float*)d_in[11];
  const float* bw      = (const float*)d_in[12];
  const float* bb      = (const float*)d_in[13];
  const float* proj_w  = (const float*)d_in[14];
  const float* proj_b  = (const float*)d_in[15];
  const float* rpb_tab = (const float*)d_in[16];
  const int*   rpb_idx = (const int*)d_in[17];
  float* out = (float*)d_out;

  char* ws = (char*)d_ws;
  float* tvec   = (float*)(ws);                    // 2048*1152*4 = 9437184
  float* inv1pg = (float*)(ws + 9437184);          // 8192
  float* nbias  = (float*)(ws + 9445376);          // 98304
  u16*   qkvwt  = (u16*)  (ws + 9543680);          // packed 72*12*512*2 = 884736
  u16*   projwt = (u16*)  (ws + 10428416);         // packed 24*12*512*2 = 294912
  u16*   rpbz   = (u16*)  (ws + 10723328);         // 12*64*64*2 = 98304 (bf16)
  u16*   attw   = (u16*)  (ws + 10821632);         // 2048*64*384*2 = 100663296 (total 111484928)

  k_aux<<<4160, 256, 0, stream>>>(qkv_w, proj_w, rpb_tab, rpb_idx,
                                  sigma, w1, b1, w2, b2, gw, gb, bw, bb,
                                  temb, qkvt_w, qkv_b,
                                  qkvwt, projwt, rpbz, inv1pg, nbias, tvec);
  k_attn<<<1024, 512, 0, stream>>>(x, tvec, inv1pg, nbias, qkvwt, rpbz, attw);
  k_proj<<<2048, 512, 0, stream>>>(attw, projwt, proj_b, out);
}

// Round 18
// 372.821 us; speedup vs baseline: 1.0709x; 1.0709x over previous
//
#include <hip/hip_runtime.h>
#include <hip/hip_bf16.h>

#define B_TOT 2048
#define SEQ 64
#define CH 384
#define NH 12
#define HD 32
#define NC3 1152
#define LDP 392          // padded bf16 row stride for s_x / s_att (784 B)
#define QKS 40           // q/k tile row stride in u16 (80 B)
#define VS 72            // vt row stride in u16
#define HDSZ 7424        // per-(batch,head) u16: q 64*40 | k 64*40 | vt 32*72
#define NTSZ 6144        // packed weight: u16 per n-tile (12 kt * 512)
#define QK_SCALE 0.17677669529663687f

typedef __attribute__((ext_vector_type(8))) short short8;   // 8 x bf16 MFMA frag
typedef __attribute__((ext_vector_type(4))) short short4v;
typedef __attribute__((ext_vector_type(4))) float f32x4;
typedef unsigned short u16;

__device__ __forceinline__ u16 f2bf(float f) {              // native cvt (measured: passes)
  __hip_bfloat16 h = __float2bfloat16(f);
  return *reinterpret_cast<u16*>(&h);
}
__device__ __forceinline__ float bf2f(u16 u) {
  return __uint_as_float(((unsigned int)u) << 16);
}

// 16B-granule XOR swizzle for the P LDS tile [64][64] bf16 (stride 64)
__device__ __forceinline__ int pswz(int row, int col) {
  return row * 64 + ((((col >> 3) ^ (row & 7)) << 3) | (col & 7));
}

// packed-weight dst index for element (k, n): fragment-major [nt][kt][q16][g4][e]
__device__ __forceinline__ int wpack(int k, int n) {
  int nt = n >> 4, q16 = n & 15;
  int kt = k >> 5, g4 = (k >> 3) & 3, e = k & 7;
  return ((nt * 12 + kt) * 64 + q16 * 4 + g4) * 8 + e;
}

// ---------------- K_AUX: one launch for prep + trunk + tvec ----------------------------------
__global__ __launch_bounds__(256) void k_aux(
    const float* __restrict__ qkv_w, const float* __restrict__ proj_w,
    const float* __restrict__ rpb_table, const int* __restrict__ rpb_index,
    const float* __restrict__ sigma, const float* __restrict__ w1,
    const float* __restrict__ b1, const float* __restrict__ w2,
    const float* __restrict__ b2, const float* __restrict__ gw,
    const float* __restrict__ gb, const float* __restrict__ bw,
    const float* __restrict__ bb, const float* __restrict__ temb,
    const float* __restrict__ qkvt_w, const float* __restrict__ qkv_b,
    u16* __restrict__ qkvwt, u16* __restrict__ projwt, u16* __restrict__ rpbz,
    float* __restrict__ inv1pg, float* __restrict__ nbias, float* __restrict__ tvec)
{
  __shared__ float shmem[16 * 384];
  const int bid = blockIdx.x;
  const int tid = threadIdx.x;

  if (bid < 2496) {                       // ---- prep (packed fragment-major weights) ----
    int idx = bid * 256 + tid;
    if (idx < CH * NC3) {
      int k = idx / NC3, n = idx - k * NC3;
      qkvwt[wpack(k, n)] = f2bf(qkv_w[idx]);
      return;
    }
    idx -= CH * NC3;
    if (idx < CH * CH) {
      int k = idx / CH, n = idx - k * CH;
      projwt[wpack(k, n)] = f2bf(proj_w[idx]);
      return;
    }
    idx -= CH * CH;
    if (idx < NH * SEQ * SEQ) {
      int h = idx >> 12, j = (idx >> 6) & 63, q = idx & 63;
      int jt = j >> 4, g4j = (j >> 2) & 3, r = j & 3;
      int qt = q >> 4, q16 = q & 15;
      int dst = (h * 16 + jt * 4 + qt) * 256 + g4j * 64 + q16 * 4 + r;
      rpbz[dst] = f2bf(rpb_table[rpb_index[q * 64 + j] * NH + h]);
    }
    return;
  }
  if (bid < 3008) {                       // ---- trunk (4 batches per block) ----
    float* sh = shmem;                    // [4][64]
    const int bt = tid >> 6, j = tid & 63;
    const int b = (bid - 2496) * 4 + bt;
    float ls = logf(fmaxf(sigma[b], 1e-6f));
    float z = fmaf(ls, w1[j], b1[j]);
    z = z / (1.f + __expf(-z));
    sh[bt * 64 + j] = z;
    __syncthreads();
    float a = b2[j];
    #pragma unroll 8
    for (int i = 0; i < 64; ++i) a = fmaf(sh[bt * 64 + i], w2[i * 64 + j], a);
    a = a / (1.f + __expf(-a));
    __syncthreads();
    sh[bt * 64 + j] = a;
    __syncthreads();
    if (j == 0) {
      float zg = gb[0];
      #pragma unroll 8
      for (int i = 0; i < 64; ++i) zg = fmaf(sh[bt * 64 + i], gw[i], zg);
      float gate = 1.f / (1.f + __expf(-zg));
      inv1pg[b] = 1.f / (1.f + gate);
    }
    if (j < NH) {
      float zb = bb[j];
      #pragma unroll 8
      for (int i = 0; i < 64; ++i) zb = fmaf(sh[bt * 64 + i], bw[i * NH + j], zb);
      nbias[b * NH + j] = zb;
    }
    return;
  }
  {                                       // ---- tvec ----
    const int bi = bid - 3008;
    const int brow = bi / 9, cseg = bi - brow * 9;
    const int cb = cseg * 128;
    for (int idx = tid; idx < 16 * 384; idx += 256) {
      int r = idx / 384, k = idx - r * 384;
      shmem[idx] = temb[(brow * 16 + r) * 384 + k];
    }
    __syncthreads();
    int cl = tid & 127, half = tid >> 7;
    float acc[8];
    #pragma unroll
    for (int i = 0; i < 8; ++i) acc[i] = 0.f;
    #pragma unroll 4
    for (int k = 0; k < 384; ++k) {
      float w = qkvt_w[k * NC3 + cb + cl];
      #pragma unroll
      for (int i = 0; i < 8; ++i) acc[i] = fmaf(shmem[(half * 8 + i) * 384 + k], w, acc[i]);
    }
    float qb = qkv_b[cb + cl];
    #pragma unroll
    for (int i = 0; i < 8; ++i)
      tvec[(brow * 16 + half * 8 + i) * NC3 + cb + cl] = acc[i] + qb;
  }
}

// ---------------- phase-A gemm: NT n-tiles x 8 m-tiles (2 batches), packed weights -----------
// SW=true (q/k waves): swapped operands -> acc holds D^T (4 consecutive FEATURES per lane),
// enabling vector epilogue writes. s_hd layout unchanged. SW=false (v waves): normal order.
template<int NT, bool SW>
__device__ __forceinline__ void gemm_qkv(f32x4 (&acc)[8][2],
                                         const u16* __restrict__ sx,
                                         const u16* __restrict__ qkvwt,
                                         int g, int nt0, int q16, int g4)
{
  const f32x4 fz = {0.f, 0.f, 0.f, 0.f};
  const u16* bp[NT];
  #pragma unroll
  for (int i = 0; i < NT; ++i) {
    int nt = nt0 + i;
    int hj = nt / 6, wi = nt - hj * 6;
    int mh = wi >> 1, hf = wi & 1;
    int ntg = mh * 24 + (g * 2 + hj) * 2 + hf;      // global n-tile index (of 72)
    bp[i] = qkvwt + ntg * NTSZ + q16 * 32 + g4 * 8; // wave reads contiguous 1 KB per (nt,kt)
  }
  #pragma unroll
  for (int m = 0; m < 8; ++m)
    #pragma unroll
    for (int i = 0; i < NT; ++i) acc[m][i] = fz;
  #pragma unroll 2
  for (int kt = 0; kt < 12; ++kt) {
    short8 af[8];
    #pragma unroll
    for (int m = 0; m < 8; ++m)
      af[m] = *reinterpret_cast<const short8*>(&sx[(m * 16 + q16) * LDP + kt * 32 + g4 * 8]);
    #pragma unroll
    for (int i = 0; i < NT; ++i) {
      short8 bf = *reinterpret_cast<const short8*>(bp[i] + kt * 512);
      #pragma unroll
      for (int m = 0; m < 8; ++m) {
        if (SW) acc[m][i] = __builtin_amdgcn_mfma_f32_16x16x32_bf16(bf, af[m], acc[m][i], 0, 0, 0);
        else    acc[m][i] = __builtin_amdgcn_mfma_f32_16x16x32_bf16(af[m], bf, acc[m][i], 0, 0, 0);
      }
    }
  }
}

// ---------------- phase-A epilogue: +tvec, scale, write q/k/vt to s_hd -----------------------
// SW=true: q/k path, acc = D^T -> lane holds 4 consecutive features at token q16 -> short4v.
// SW=false: v path, acc normal -> lane holds 4 consecutive tokens at feature cof -> short4v.
template<int NT, bool SW>
__device__ __forceinline__ void epi_qkv(const f32x4 (&acc)[8][2], u16* __restrict__ shd,
                                        const float* __restrict__ tvb,
                                        int g, int nt0, int q16, int g4)
{
  #pragma unroll
  for (int i = 0; i < NT; ++i) {
    int nt = nt0 + i;
    int hj = nt / 6, wi = nt - hj * 6;
    int mh = wi >> 1, hf = wi & 1;
    if (SW) {
      // q (mh==0) or k (mh==1): feature-major acc
      int cbase = mh * CH + (g * 2 + hj) * HD + hf * 16 + 4 * g4;
      float4 tv0 = *reinterpret_cast<const float4*>(&tvb[cbase]);
      float4 tv1 = *reinterpret_cast<const float4*>(&tvb[NC3 + cbase]);
      float scl = (mh == 0) ? QK_SCALE : 1.f;
      int off = (mh == 1 ? 2560 : 0) + hf * 16 + 4 * g4;
      #pragma unroll
      for (int m = 0; m < 8; ++m) {
        int bt = m >> 2;
        u16* hbase = &shd[(bt * 2 + hj) * HDSZ];
        int token = (m & 3) * 16 + q16;
        f32x4 a = acc[m][i];
        float4 tv = bt ? tv1 : tv0;
        short4v pk;
        pk[0] = (short)f2bf((a[0] + tv.x) * scl);
        pk[1] = (short)f2bf((a[1] + tv.y) * scl);
        pk[2] = (short)f2bf((a[2] + tv.z) * scl);
        pk[3] = (short)f2bf((a[3] + tv.w) * scl);
        *reinterpret_cast<short4v*>(&hbase[off + token * QKS]) = pk;
      }
    } else {
      // v: token-major acc -> transposed vt write (contiguous tokens)
      int c = mh * CH + (g * 2 + hj) * HD + hf * 16 + q16;
      float tv0 = tvb[c], tv1 = tvb[NC3 + c];
      int cof = hf * 16 + q16;
      #pragma unroll
      for (int m = 0; m < 8; ++m) {
        int bt = m >> 2;
        u16* hbase = &shd[(bt * 2 + hj) * HDSZ];
        int mrow = (m & 3) * 16 + g4 * 4;
        f32x4 a = acc[m][i];
        float tvv = bt ? tv1 : tv0;
        short4v pk;
        #pragma unroll
        for (int r = 0; r < 4; ++r) pk[r] = (short)f2bf(a[r] + tvv);
        *reinterpret_cast<short4v*>(&hbase[5120 + cof * VS + mrow]) = pk;
      }
    }
  }
}

// ---------------- K3: per-(2-batch) QKV -> attention -> att (bf16, to ws) --------------------
// 512 thr = 8 waves = 2 waves/SIMD; LDS 159744 B -> 1 block/CU. (R16 structure: measured best.)
// Region R3: gemm(g+1) shares the unbarriered region with pass2(g). rpb loads hoisted above
// bar_b (no s_hd dependency) so their latency hides under the epilogue + barrier drain.
__global__ __launch_bounds__(512, 2) void k_attn(
    const float* __restrict__ x, const float* __restrict__ tvec,
    const float* __restrict__ inv1pg, const float* __restrict__ nbias,
    const u16* __restrict__ qkvwt, const u16* __restrict__ rpbz,
    u16* __restrict__ attw)
{
  __shared__ __align__(16) u16 s_x[128 * LDP];    // x[2 batches] bf16 (100352 B)
  __shared__ __align__(16) u16 s_hd[4 * HDSZ];    // [batch][head]: q|k|vt (59392 B)
  const f32x4 fz = {0.f, 0.f, 0.f, 0.f};

  const int b0 = blockIdx.x * 2;
  const int tid = threadIdx.x;
  const int w = tid >> 6, l = tid & 63;
  const int q16 = l & 15, g4 = l >> 4;

  // ---- stage x for 2 batches (fp32 -> bf16), coalesced float4 ----
  {
    const float* xb = x + (size_t)b0 * (SEQ * CH);
    #pragma unroll 4
    for (int it = 0; it < 24; ++it) {
      int fi = it * 512 + tid;            // float4 index; 96 per row, 128 rows
      int row = fi / 96, c4 = fi - row * 96;
      const float4 a = *reinterpret_cast<const float4*>(xb + fi * 4);
      short4v v;
      v[0] = (short)f2bf(a.x); v[1] = (short)f2bf(a.y);
      v[2] = (short)f2bf(a.z); v[3] = (short)f2bf(a.w);
      *reinterpret_cast<short4v*>(&s_x[row * LDP + c4 * 4]) = v;
    }
  }
  __syncthreads();

  const float invb0 = inv1pg[b0], invb1 = inv1pg[b0 + 1];
  const float* tvb = tvec + (size_t)b0 * NC3;

  const int nt0 = (w < 4) ? 2 * w : 8 + (w - 4);
  const int wi0 = nt0 % 6;
  const bool swp = ((wi0 >> 1) != 2);     // q/k waves use swapped-operand MFMA

  f32x4 acc[8][2];
  // prologue: gemm for group 0
  if (w < 4) { if (swp) gemm_qkv<2, true>(acc, s_x, qkvwt, 0, nt0, q16, g4);
               else     gemm_qkv<2, false>(acc, s_x, qkvwt, 0, nt0, q16, g4); }
  else       { if (swp) gemm_qkv<1, true>(acc, s_x, qkvwt, 0, nt0, q16, g4);
               else     gemm_qkv<1, false>(acc, s_x, qkvwt, 0, nt0, q16, g4); }

  for (int g = 0; g < 6; ++g) {
    if (g) __syncthreads();               // bar_a: pass2(g-1) done reading s_hd
    // ===== epilogue(g): acc -> s_hd =====
    if (w < 4) { if (swp) epi_qkv<2, true>(acc, s_hd, tvb, g, nt0, q16, g4);
                 else     epi_qkv<2, false>(acc, s_hd, tvb, g, nt0, q16, g4); }
    else       { if (swp) epi_qkv<1, true>(acc, s_hd, tvb, g, nt0, q16, g4);
                 else     epi_qkv<1, false>(acc, s_hd, tvb, g, nt0, q16, g4); }

    // hoisted rpb loads (global only, no s_hd dep) — latency hides under barrier drain
    short4v rp4h[2][4];
    #pragma unroll
    for (int t = 0; t < 2; ++t) {
      const int tau = w * 2 + t;
      const int cmb = tau >> 2, qt = tau & 3;
      const int hh = cmb & 1;
      const int h = g * 2 + hh;
      #pragma unroll
      for (int jt = 0; jt < 4; ++jt)
        rp4h[t][jt] = *reinterpret_cast<const short4v*>(
            &rpbz[(h * 16 + jt * 4 + qt) * 256 + g4 * 64 + q16 * 4]);
    }
    __syncthreads();                      // bar_b: q/k/vt ready

    // ===== pass1: QK^T + gate + softmax for tasks t=0,1 =====
    f32x4 st2[2][4];
    #pragma unroll
    for (int t = 0; t < 2; ++t) {
      const int tau = w * 2 + t;
      const int cmb = tau >> 2, qt = tau & 3;
      const int bt = cmb >> 1, hh = cmb & 1;
      const int h = g * 2 + hh;
      const u16* sq = &s_hd[cmb * HDSZ];
      const u16* sk = sq + 2560;
      const float inv = bt ? invb1 : invb0;
      const float nb = nbias[(b0 + bt) * NH + h];

      short8 bq = *reinterpret_cast<const short8*>(&sq[(qt * 16 + q16) * QKS + g4 * 8]);
      #pragma unroll
      for (int jt = 0; jt < 4; ++jt) {
        short8 ak = *reinterpret_cast<const short8*>(&sk[(jt * 16 + q16) * QKS + g4 * 8]);
        st2[t][jt] = __builtin_amdgcn_mfma_f32_16x16x32_bf16(ak, bq, fz, 0, 0, 0);
      }
      float mx = -1e30f;
      #pragma unroll
      for (int jt = 0; jt < 4; ++jt)
        #pragma unroll
        for (int r = 0; r < 4; ++r) {
          float s = fmaf(st2[t][jt][r], inv, fmaf(bf2f((u16)rp4h[t][jt][r]), inv, nb));
          st2[t][jt][r] = s;
          mx = fmaxf(mx, s);
        }
      mx = fmaxf(mx, __shfl_xor(mx, 16));
      mx = fmaxf(mx, __shfl_xor(mx, 32));
      float sum = 0.f;
      #pragma unroll
      for (int jt = 0; jt < 4; ++jt)
        #pragma unroll
        for (int r = 0; r < 4; ++r) {
          float p = __expf(st2[t][jt][r] - mx);
          st2[t][jt][r] = p;
          sum += p;
        }
      sum += __shfl_xor(sum, 16);
      sum += __shfl_xor(sum, 32);
      float rn = 1.f / sum;
      #pragma unroll
      for (int jt = 0; jt < 4; ++jt)
        #pragma unroll
        for (int r = 0; r < 4; ++r) st2[t][jt][r] *= rn;
    }
    __syncthreads();                      // bar_c: all q/k reads done before P overlay

    // ===== region R3: gemm(g+1) interleaved with pass2(g) by the scheduler =====
    if (g < 5) {
      if (w < 4) { if (swp) gemm_qkv<2, true>(acc, s_x, qkvwt, g + 1, nt0, q16, g4);
                   else     gemm_qkv<2, false>(acc, s_x, qkvwt, g + 1, nt0, q16, g4); }
      else       { if (swp) gemm_qkv<1, true>(acc, s_x, qkvwt, g + 1, nt0, q16, g4);
                   else     gemm_qkv<1, false>(acc, s_x, qkvwt, g + 1, nt0, q16, g4); }
    }
    #pragma unroll
    for (int t = 0; t < 2; ++t) {
      const int tau = w * 2 + t;
      const int cmb = tau >> 2, qt = tau & 3;
      const int bt = cmb >> 1, hh = cmb & 1;
      const int h = g * 2 + hh;
      u16* sq = &s_hd[cmb * HDSZ];
      const u16* svt = sq + 5120;
      u16* P = sq;                        // 64x64 bf16 swizzled, overlays q+k

      #pragma unroll
      for (int jt = 0; jt < 4; ++jt) {
        short4v pk;
        #pragma unroll
        for (int r = 0; r < 4; ++r) pk[r] = (short)f2bf(st2[t][jt][r]);
        *reinterpret_cast<short4v*>(&P[pswz(qt * 16 + q16, jt * 16 + 4 * g4)]) = pk;
      }
      f32x4 o[2];
      o[0] = fz; o[1] = fz;
      #pragma unroll
      for (int kk = 0; kk < 2; ++kk) {
        short8 ap = *reinterpret_cast<const short8*>(
            &P[pswz(qt * 16 + q16, kk * 32 + g4 * 8)]);
        #pragma unroll
        for (int dt = 0; dt < 2; ++dt) {
          short8 bv = *reinterpret_cast<const short8*>(
              &svt[(dt * 16 + q16) * VS + kk * 32 + g4 * 8]);
          o[dt] = __builtin_amdgcn_mfma_f32_16x16x32_bf16(ap, bv, o[dt], 0, 0, 0);
        }
      }
      u16* ab = attw + (size_t)(b0 + bt) * (SEQ * CH);
      #pragma unroll
      for (int dt = 0; dt < 2; ++dt)
        #pragma unroll
        for (int r = 0; r < 4; ++r)
          ab[(qt * 16 + g4 * 4 + r) * CH + h * HD + dt * 16 + q16] = f2bf(o[dt][r]);
    }
  }
}

// ---------------- K4: proj GEMM out = att @ projwt^T + b; 64-row tiles, packed weights -------
// (R16 version: direct float4 stores — measured best.)
__global__ __launch_bounds__(512, 4) void k_proj(
    const u16* __restrict__ attw, const u16* __restrict__ projwt,
    const float* __restrict__ proj_b, float* __restrict__ out)
{
  __shared__ __align__(16) u16 s_a[64 * LDP];     // att tile bf16 (50176 B)
  const f32x4 fz = {0.f, 0.f, 0.f, 0.f};
  const int tid = threadIdx.x;
  const int w = tid >> 6, l = tid & 63;
  const int q16 = l & 15, g4 = l >> 4;
  const size_t row0 = (size_t)blockIdx.x * 64;

  {
    const u16* ab = attw + row0 * CH;
    #pragma unroll
    for (int it = 0; it < 6; ++it) {
      int slot = it * 512 + tid;
      int row = slot / 48, c8 = slot - row * 48;   // 48 short8 per 384-col row
      short8 v = *reinterpret_cast<const short8*>(ab + row * CH + c8 * 8);
      *reinterpret_cast<short8*>(&s_a[row * LDP + c8 * 8]) = v;
    }
  }
  __syncthreads();

  const u16* bpw[3]; float4 pb4[3];
  #pragma unroll
  for (int i = 0; i < 3; ++i) {
    int nt = w * 3 + i;
    bpw[i] = projwt + nt * NTSZ + q16 * 32 + g4 * 8;   // contiguous 1 KB per (nt,kt)
    pb4[i] = *reinterpret_cast<const float4*>(&proj_b[nt * 16 + 4 * g4]);
  }
  f32x4 acc[4][3];
  #pragma unroll
  for (int m = 0; m < 4; ++m)
    #pragma unroll
    for (int i = 0; i < 3; ++i) acc[m][i] = fz;
  #pragma unroll 2
  for (int kt = 0; kt < 12; ++kt) {
    short8 af[4];
    #pragma unroll
    for (int m = 0; m < 4; ++m)
      af[m] = *reinterpret_cast<const short8*>(&s_a[(m * 16 + q16) * LDP + kt * 32 + g4 * 8]);
    short8 bf[3];
    #pragma unroll
    for (int i = 0; i < 3; ++i)
      bf[i] = *reinterpret_cast<const short8*>(bpw[i] + kt * 512);
    #pragma unroll
    for (int i = 0; i < 3; ++i)
      #pragma unroll
      for (int m = 0; m < 4; ++m)
        acc[m][i] = __builtin_amdgcn_mfma_f32_16x16x32_bf16(bf[i], af[m], acc[m][i], 0, 0, 0);
  }
  float* ob = out + row0 * CH;
  #pragma unroll
  for (int i = 0; i < 3; ++i) {
    int cb = (w * 3 + i) * 16 + 4 * g4;
    #pragma unroll
    for (int m = 0; m < 4; ++m) {
      float4 v;
      v.x = acc[m][i][0] + pb4[i].x;
      v.y = acc[m][i][1] + pb4[i].y;
      v.z = acc[m][i][2] + pb4[i].z;
      v.w = acc[m][i][3] + pb4[i].w;
      *reinterpret_cast<float4*>(&ob[(m * 16 + q16) * CH + cb]) = v;
    }
  }
}

// ---------------- launcher ----------------
extern "C" void kernel_launch(void* const* d_in, const int* in_sizes, int n_in,
                              void* d_out, int out_size, void* d_ws, size_t ws_size,
                              hipStream_t stream) {
  const float* x       = (const float*)d_in[0];
  const float* temb    = (const float*)d_in[1];
  const float* sigma   = (const float*)d_in[2];
  const float* qkv_w   = (const float*)d_in[3];
  const float* qkv_b   = (const float*)d_in[4];
  const float* qkvt_w  = (const float*)d_in[5];
  const float* w1      = (const float*)d_in[6];
  const float* b1      = (const float*)d_in[7];
  const float* w2      = (const float*)d_in[8];
  const float* b2      = (const float*)d_in[9];
  const float* gw      = (const float*)d_in[10];
  const float* gb      = (const float*)d_in[11];
  const float* bw      = (const float*)d_in[12];
  const float* bb      = (const float*)d_in[13];
  const float* proj_w  = (const float*)d_in[14];
  const float* proj_b  = (const float*)d_in[15];
  const float* rpb_tab = (const float*)d_in[16];
  const int*   rpb_idx = (const int*)d_in[17];
  float* out = (float*)d_out;

  char* ws = (char*)d_ws;
  float* tvec   = (float*)(ws);                    // 2048*1152*4 = 9437184
  float* inv1pg = (float*)(ws + 9437184);          // 8192
  float* nbias  = (float*)(ws + 9445376);          // 98304
  u16*   qkvwt  = (u16*)  (ws + 9543680);          // packed 72*12*512*2 = 884736
  u16*   projwt = (u16*)  (ws + 10428416);         // packed 24*12*512*2 = 294912
  u16*   rpbz   = (u16*)  (ws + 10723328);         // 12*64*64*2 = 98304 (bf16)
  u16*   attw   = (u16*)  (ws + 10821632);         // 2048*64*384*2 = 100663296 (total 111484928)

  k_aux<<<4160, 256, 0, stream>>>(qkv_w, proj_w, rpb_tab, rpb_idx,
                                  sigma, w1, b1, w2, b2, gw, gb, bw, bb,
                                  temb, qkvt_w, qkv_b,
                                  qkvwt, projwt, rpbz, inv1pg, nbias, tvec);
  k_attn<<<1024, 512, 0, stream>>>(x, tvec, inv1pg, nbias, qkvwt, rpbz, attw);
  k_proj<<<2048, 512, 0, stream>>>(attw, projwt, proj_b, out);
}